// Round 4
// baseline (952.406 us; speedup 1.0000x reference)
//
#include <hip/hip_runtime.h>
#include <hip/hip_bf16.h>
#include <cstdint>

typedef __attribute__((ext_vector_type(4))) float f32x4;
typedef __attribute__((ext_vector_type(8))) short s16x8;

#define BSHIFT 13          // col window = 8192 nodes * 512 B = 4 MB (one XCD L2)
#define NWAVES 8192        // 2048 blocks * 4 waves
#define JMAX 13            // ceil(100000 / 8192)

__device__ inline unsigned short f2bf(float f) {
    unsigned u = __float_as_uint(f);
    u = (u + 0x7fffu + ((u >> 16) & 1u)) >> 16;   // round-to-nearest-even
    return (unsigned short)u;
}
__device__ inline float bf_lo(unsigned x) { return __uint_as_float(x << 16); }
__device__ inline float bf_hi(unsigned x) { return __uint_as_float(x & 0xffff0000u); }

// ---------------- W (f32) -> bf16 ----------------
__global__ void convW(const float* __restrict__ W, unsigned short* __restrict__ Wb) {
    int i = blockIdx.x * 256 + threadIdx.x;
    if (i < 256 * 256) Wb[i] = f2bf(W[i]);
}

// ---------------- X (f32) -> bf16, 8 elems/thread ----------------
__global__ __launch_bounds__(256) void convX(const float* __restrict__ X,
                                             unsigned short* __restrict__ Xb) {
    size_t i = ((size_t)blockIdx.x * 256 + threadIdx.x) * 8;
    f32x4 x0 = *(const f32x4*)(X + i);
    f32x4 x1 = *(const f32x4*)(X + i + 4);
    s16x8 r;
    r[0] = (short)f2bf(x0.x); r[1] = (short)f2bf(x0.y);
    r[2] = (short)f2bf(x0.z); r[3] = (short)f2bf(x0.w);
    r[4] = (short)f2bf(x1.x); r[5] = (short)f2bf(x1.y);
    r[6] = (short)f2bf(x1.z); r[7] = (short)f2bf(x1.w);
    *(s16x8*)(Xb + i) = r;
}

// ---------------- h = X @ W^T + b (bf16 in/out, IN-PLACE: Xb == Hb)
// + fused a1/a2 per-node score epilogue.
// In-place safety: each block touches only its own 32 rows; the
// __syncthreads() after the K-loop ensures ALL waves' X reads complete
// before ANY wave's H writes. (No __restrict__ on the aliasing pair.)
__global__ __launch_bounds__(256) void gemm_h(
    const unsigned short* Xb, const unsigned short* __restrict__ Wb,
    const float* __restrict__ bvec, unsigned short* Hb,
    const float* __restrict__ wa1, const float* __restrict__ ba1,
    const float* __restrict__ wa2, const float* __restrict__ ba2,
    float* __restrict__ a1, float* __restrict__ a2) {
    __shared__ float a1p[4][32], a2p[4][32];
    const int lane = threadIdx.x & 63;
    const int wave = threadIdx.x >> 6;
    const int l15 = lane & 15, quad = lane >> 4;
    const int nbase = blockIdx.x * 32;
    const int obase = wave * 64;

    f32x4 acc[2][4] = {};
#pragma unroll
    for (int k = 0; k < 256; k += 32) {
        s16x8 afr[2];
#pragma unroll
        for (int mt = 0; mt < 2; ++mt)
            afr[mt] = *(const s16x8*)(Xb + (size_t)(nbase + mt * 16 + l15) * 256 + k + quad * 8);
#pragma unroll
        for (int t = 0; t < 4; ++t) {
            s16x8 bfr = *(const s16x8*)(Wb + (size_t)(obase + t * 16 + l15) * 256 + k + quad * 8);
            acc[0][t] = __builtin_amdgcn_mfma_f32_16x16x32_bf16(afr[0], bfr, acc[0][t], 0, 0, 0);
            acc[1][t] = __builtin_amdgcn_mfma_f32_16x16x32_bf16(afr[1], bfr, acc[1][t], 0, 0, 0);
        }
    }

    __syncthreads();   // all X reads done before any H writes (in-place)

    float p1[2][4] = {}, p2[2][4] = {};
#pragma unroll
    for (int t = 0; t < 4; ++t) {
        int o = obase + t * 16 + l15;
        float bv = bvec[o];
        float w1t = wa1[o], w2t = wa2[o];
#pragma unroll
        for (int mt = 0; mt < 2; ++mt) {
#pragma unroll
            for (int r = 0; r < 4; ++r) {
                int node = nbase + mt * 16 + quad * 4 + r;
                float hv = acc[mt][t][r] + bv;
                Hb[(size_t)node * 256 + o] = f2bf(hv);
                p1[mt][r] += hv * w1t;
                p2[mt][r] += hv * w2t;
            }
        }
    }
    // reduce across the 16 l15-lanes (same quad), then across waves via LDS
#pragma unroll
    for (int mt = 0; mt < 2; ++mt) {
#pragma unroll
        for (int r = 0; r < 4; ++r) {
            float v1 = p1[mt][r], v2 = p2[mt][r];
#pragma unroll
            for (int m = 1; m <= 8; m <<= 1) {
                v1 += __shfl_xor(v1, m);
                v2 += __shfl_xor(v2, m);
            }
            if (l15 == 0) {
                a1p[wave][mt * 16 + quad * 4 + r] = v1;
                a2p[wave][mt * 16 + quad * 4 + r] = v2;
            }
        }
    }
    __syncthreads();
    if (threadIdx.x < 32) {
        float s1 = ba1[0], s2 = ba2[0];
#pragma unroll
        for (int w = 0; w < 4; ++w) {
            s1 += a1p[w][threadIdx.x];
            s2 += a2p[w][threadIdx.x];
        }
        a1[nbase + threadIdx.x] = s1;
        a2[nbase + threadIdx.x] = s2;
    }
}

// ---------------- bucket-major CSR build ----------------
// key = (col >> BSHIFT) * n + row ; rank = ordinal within (bucket,row)
__global__ void hist2(const int* __restrict__ rows, const int* __restrict__ cols,
                      int* __restrict__ cnt2, int* __restrict__ rank, int n, int e) {
    int i = blockIdx.x * 256 + threadIdx.x;
    if (i < e) {
        int key = (cols[i] >> BSHIFT) * n + rows[i];
        rank[i] = atomicAdd(&cnt2[key], 1);
    }
}

__global__ __launch_bounds__(256) void scan1(
    const int* __restrict__ cnt, int* __restrict__ off, int* __restrict__ bsum, int n) {
    __shared__ int lds[256];
    const int tid = threadIdx.x;
    const int base = blockIdx.x * 2048 + tid * 8;
    int v[8];
    int run = 0;
#pragma unroll
    for (int j = 0; j < 8; ++j) {
        int idx = base + j;
        int x = (idx < n) ? cnt[idx] : 0;
        run += x;
        v[j] = run;
    }
    lds[tid] = run;
    __syncthreads();
#pragma unroll
    for (int ofs = 1; ofs < 256; ofs <<= 1) {
        int t = (tid >= ofs) ? lds[tid - ofs] : 0;
        __syncthreads();
        lds[tid] += t;
        __syncthreads();
    }
    int pre = lds[tid] - run;
#pragma unroll
    for (int j = 0; j < 8; ++j) {
        int idx = base + j;
        if (idx < n) off[1 + idx] = v[j] + pre;
    }
    if (tid == 255) bsum[blockIdx.x] = lds[255];
}

// parallel single-block exclusive scan over up to 2048 block sums
__global__ __launch_bounds__(256) void scan2p(int* __restrict__ bsum,
                                              int* __restrict__ off, int nb) {
    __shared__ int lds[256];
    const int tid = threadIdx.x;
    const int base = tid * 8;
    int x[8], v[8];
    int run = 0;
#pragma unroll
    for (int j = 0; j < 8; ++j) {
        int idx = base + j;
        x[j] = (idx < nb) ? bsum[idx] : 0;
        run += x[j];
        v[j] = run;
    }
    lds[tid] = run;
    __syncthreads();
#pragma unroll
    for (int ofs = 1; ofs < 256; ofs <<= 1) {
        int t = (tid >= ofs) ? lds[tid - ofs] : 0;
        __syncthreads();
        lds[tid] += t;
        __syncthreads();
    }
    int pre = lds[tid] - run;
#pragma unroll
    for (int j = 0; j < 8; ++j) {
        int idx = base + j;
        if (idx < nb) bsum[idx] = pre + v[j] - x[j];   // exclusive
    }
    if (tid == 0) off[0] = 0;
}

__global__ __launch_bounds__(256) void scan3(
    const int* __restrict__ bsum, int* __restrict__ off, int n) {
    int add = bsum[blockIdx.x];
    int base = blockIdx.x * 2048 + threadIdx.x * 8;
#pragma unroll
    for (int j = 0; j < 8; ++j) {
        int idx = base + j;
        if (idx < n) off[1 + idx] += add;
    }
}

// scatter edges into bucket-major CSR; precompute ev = exp(leaky(a1+a2))
// packed as {col, ev_bits} so the aggregate reads one 8B stream per edge
__global__ void scatter2(const int* __restrict__ rows, const int* __restrict__ cols,
                         const int* __restrict__ rank, const int* __restrict__ off2,
                         const float* __restrict__ a1, const float* __restrict__ a2,
                         uint2* __restrict__ CE, int n, int e) {
    int i = blockIdx.x * 256 + threadIdx.x;
    if (i < e) {
        int r = rows[i], c = cols[i];
        int key = (c >> BSHIFT) * n + r;
        int p = off2[key] + rank[i];
        float v = a1[r] + a2[c];
        v = (v > 0.0f) ? v : 0.01f * v;
        float ev = __expf(v);
        CE[p] = make_uint2((unsigned)c, __float_as_uint(ev));
    }
}

// ---------------- persistent bucket-sweep softmax + aggregation ----------------
// 2048 blocks * 4 waves = 8192 waves; wave owns nodes wgid + j*8192 (13 max).
// All waves sweep col-buckets in the same order -> concurrent Hb gathers fall
// in one ~4 MB window -> L2 hits instead of fabric misses.
__global__ __launch_bounds__(256, 4) void aggregate_p(
    const int* __restrict__ off2, const uint2* __restrict__ CE,
    const unsigned short* __restrict__ Hb, float* __restrict__ out,
    int n, int nbuck) {
    const int lane = threadIdx.x & 63;
    const int wave = threadIdx.x >> 6;
    const int wgid = blockIdx.x * 4 + wave;
    const int cbase = lane * 4;

    f32x4 acc[JMAX];
    float s[JMAX];
#pragma unroll
    for (int j = 0; j < JMAX; ++j) {
        acc[j] = (f32x4){0.0f, 0.0f, 0.0f, 0.0f};
        s[j] = 0.0f;
    }

    for (int b = 0; b < nbuck; ++b) {
        const int* ob = off2 + (size_t)b * n;
#pragma unroll
        for (int j = 0; j < JMAX; ++j) {
            int node = wgid + j * NWAVES;
            if (node < n) {
                int i = ob[node];
                int en = ob[node + 1];
                for (; i + 1 < en; i += 2) {
                    uint2 ce0 = CE[i], ce1 = CE[i + 1];
                    float ev0 = __uint_as_float(ce0.y);
                    float ev1 = __uint_as_float(ce1.y);
                    uint2 h0 = *(const uint2*)(Hb + (size_t)ce0.x * 256 + cbase);
                    uint2 h1 = *(const uint2*)(Hb + (size_t)ce1.x * 256 + cbase);
                    acc[j].x += ev0 * bf_lo(h0.x) + ev1 * bf_lo(h1.x);
                    acc[j].y += ev0 * bf_hi(h0.x) + ev1 * bf_hi(h1.x);
                    acc[j].z += ev0 * bf_lo(h0.y) + ev1 * bf_lo(h1.y);
                    acc[j].w += ev0 * bf_hi(h0.y) + ev1 * bf_hi(h1.y);
                    s[j] += ev0 + ev1;
                }
                if (i < en) {
                    uint2 ce0 = CE[i];
                    float ev0 = __uint_as_float(ce0.y);
                    uint2 h0 = *(const uint2*)(Hb + (size_t)ce0.x * 256 + cbase);
                    acc[j].x += ev0 * bf_lo(h0.x);
                    acc[j].y += ev0 * bf_hi(h0.x);
                    acc[j].z += ev0 * bf_lo(h0.y);
                    acc[j].w += ev0 * bf_hi(h0.y);
                    s[j] += ev0;
                }
            }
        }
    }
#pragma unroll
    for (int j = 0; j < JMAX; ++j) {
        int node = wgid + j * NWAVES;
        if (node < n) {
            float inv = (s[j] > 0.0f) ? 1.0f / s[j] : 0.0f;
            f32x4 o;
            o.x = acc[j].x * inv; o.y = acc[j].y * inv;
            o.z = acc[j].z * inv; o.w = acc[j].w * inv;
            *(f32x4*)(out + (size_t)node * 256 + cbase) = o;
        }
    }
}

extern "C" void kernel_launch(void* const* d_in, const int* in_sizes, int n_in,
                              void* d_out, int out_size, void* d_ws, size_t ws_size,
                              hipStream_t stream) {
    const float* X   = (const float*)d_in[0];
    const int*   idx = (const int*)d_in[1];
    const float* W   = (const float*)d_in[2];
    const float* b   = (const float*)d_in[3];
    const float* wa1 = (const float*)d_in[4];
    const float* ba1 = (const float*)d_in[5];
    const float* wa2 = (const float*)d_in[6];
    const float* ba2 = (const float*)d_in[7];
    float* out = (float*)d_out;

    const int n = in_sizes[0] / 256;  // 100000
    const int e = in_sizes[1] / 2;    // 3200000
    const int nbuck = (n + (1 << BSHIFT) - 1) >> BSHIFT;  // 13
    const int n2 = nbuck * n;                             // 1.3M keys

    char* p = (char*)d_ws;
    auto alloc = [&](size_t bytes) -> char* {
        char* r = p;
        p += (bytes + 255) & ~(size_t)255;
        return r;
    };
    unsigned short* XH = (unsigned short*)alloc((size_t)n * 256 * 2);  // Xb then Hb
    unsigned short* Wb = (unsigned short*)alloc(256 * 256 * 2);
    float* a1  = (float*)alloc((size_t)n * 4);
    float* a2  = (float*)alloc((size_t)n * 4);
    int* cnt2  = (int*)alloc((size_t)n2 * 4);
    int* off2  = (int*)alloc((size_t)(n2 + 1) * 4);
    int* bsum  = (int*)alloc(2048 * 4);
    int* rank  = (int*)alloc((size_t)e * 4);
    uint2* CE  = (uint2*)alloc((size_t)e * 8);

    const int* rows   = idx;
    const int* colsIn = idx + e;

    hipMemsetAsync(cnt2, 0, (size_t)n2 * 4, stream);

    convW<<<256, 256, 0, stream>>>(W, Wb);
    convX<<<(n * 256) / (256 * 8), 256, 0, stream>>>(X, XH);
    gemm_h<<<n / 32, 256, 0, stream>>>(XH, Wb, b, XH, wa1, ba1, wa2, ba2, a1, a2);
    hist2<<<(e + 255) / 256, 256, 0, stream>>>(rows, colsIn, cnt2, rank, n, e);
    int nb2 = (n2 + 2047) / 2048;
    scan1<<<nb2, 256, 0, stream>>>(cnt2, off2, bsum, n2);
    scan2p<<<1, 256, 0, stream>>>(bsum, off2, nb2);
    scan3<<<nb2, 256, 0, stream>>>(bsum, off2, n2);
    scatter2<<<(e + 255) / 256, 256, 0, stream>>>(rows, colsIn, rank, off2, a1, a2, CE, n, e);
    aggregate_p<<<NWAVES / 4, 256, 0, stream>>>(off2, CE, XH, out, n, nbuck);
}